// Round 9
// baseline (97.643 us; speedup 1.0000x reference)
//
#include <hip/hip_runtime.h>
#include <hip/hip_bf16.h>
#include <cstdint>
#include <cstddef>

// Problem constants
#define Bsz 16384
#define Esz 16
#define Ssz 64
#define Asz 32
#define Isz 96   // S + A
#define HSz 64
#define HRz 32

#define PT 512        // prep threads
#define NTM 256       // main threads (4 waves)
#define CHUNK 256     // batch rows per main block
#define NTILE 2       // CHUNK / (4 waves * 32 rows)
#define WELEMS 13312  // per-e fragment elems: W1 6144 | rW1 3072 | W2 4096

typedef __attribute__((ext_vector_type(8))) short bf16x8;
typedef __attribute__((ext_vector_type(4))) short short4v;
typedef __attribute__((ext_vector_type(4))) float f32x4;

static __device__ __forceinline__ short f2bf(float f) {
    __hip_bfloat16 b = __float2bfloat16(f);   // pairs into v_cvt_pk_bf16_f32
    return *reinterpret_cast<short*>(&b);
}
static __device__ __forceinline__ float bf2f(short s) {
    union { uint32_t u; float f; } v; v.u = ((uint32_t)(uint16_t)s) << 16; return v.f;
}
static __device__ __forceinline__ bf16x8 pack8(float4 lo, float4 hi) {
    bf16x8 r;
    r[0] = f2bf(lo.x); r[1] = f2bf(lo.y); r[2] = f2bf(lo.z); r[3] = f2bf(lo.w);
    r[4] = f2bf(hi.x); r[5] = f2bf(hi.y); r[6] = f2bf(hi.z); r[7] = f2bf(hi.w);
    return r;
}

// ---- Prep: weights -> bf16 MFMA fragment order (proven R4/R7 layout) ----
// Fragment: lane l holds W[k = kk*32 + (l>>4)*8 + t][n = nt*16 + (l&15)], t=0..7
__global__ void prep_w(const float* __restrict__ W1, const float* __restrict__ rW1,
                       const float* __restrict__ W2, short* __restrict__ Wf) {
    int idx = blockIdx.x * blockDim.x + threadIdx.x;   // [0, Esz*WELEMS)
    int e = idx / WELEMS, r = idx - e * WELEMS;
    float v;
    if (r < 6144) {
        int nt = r / 1536, r2 = r % 1536, kk = r2 / 512, r3 = r2 % 512, l = r3 >> 3, t = r3 & 7;
        int i = kk * 32 + (l >> 4) * 8 + t, h = nt * 16 + (l & 15);
        v = W1[(size_t)e * Isz * HSz + i * HSz + h];
    } else if (r < 9216) {
        int r1 = r - 6144;
        int nt = r1 / 1536, r2 = r1 % 1536, kk = r2 / 512, r3 = r2 % 512, l = r3 >> 3, t = r3 & 7;
        int i = kk * 32 + (l >> 4) * 8 + t, h = nt * 16 + (l & 15);
        v = rW1[(size_t)e * Isz * HRz + i * HRz + h];
    } else {
        int r1 = r - 9216;
        int nt = r1 / 1024, r2 = r1 % 1024, kk = r2 / 512, r3 = r2 % 512, l = r3 >> 3, t = r3 & 7;
        int hk = kk * 32 + (l >> 4) * 8 + t, s = nt * 16 + (l & 15);
        v = W2[(size_t)e * HSz * Ssz + hk * Ssz + s];
    }
    Wf[idx] = f2bf(v);
}

// ---- Main: weights in LDS, 32 rows/wave, XCD-swizzled, 3 waves/SIMD target ----
// Swapped mfma(Wfrag, Xfrag): D lane: m = lane&15, n = nt*16 + (lane>>4)*4 + j.
__global__ __launch_bounds__(NTM, 3)
void fused_main(const float* __restrict__ state, const float* __restrict__ action,
                const short* __restrict__ Wf,
                const float* __restrict__ b1, const float* __restrict__ b2,
                const float* __restrict__ rb1, const float* __restrict__ rW2,
                const float* __restrict__ rb2,
                float* __restrict__ outS, float* __restrict__ outR)
{
    __shared__ __align__(16) short WL[WELEMS];       // 26624 B: weight fragments
    __shared__ __align__(16) short HT[4][16][68];    // 8704 B: per-wave H transpose (reused per mh)

    // ---- XCD-aware sibling swizzle (bijective over 1024 blocks) ----
    // bid = xcd + 8*e + 128*chi; chunk c = xcd + 8*chi -> all 16 e-siblings of a
    // chunk share XCD (bid%8); per-XCD X working set ~768 KB -> L2-resident.
    const int bid = blockIdx.x;
    const int xcd = bid & 7;
    const int e   = (bid >> 3) & (Esz - 1);
    const int chi = bid >> 7;
    const int c0  = (xcd + 8 * chi) * CHUNK;

    const int tid = threadIdx.x;
    const int w = tid >> 6, lane = tid & 63;
    const int lr = lane & 15, lg = lane >> 4;

    // ---- Stage weight fragments into LDS: coalesced b128 copy ----
    {
        const short* src = Wf + (size_t)e * WELEMS;
        for (int i = tid; i < WELEMS / 8; i += NTM)   // 1664 chunks of 16 B
            *(bf16x8*)&WL[i * 8] = *(const bf16x8*)&src[i * 8];
    }

    // ---- Biases packed bf16 (lane's D slots: n = nt*16 + lg*4 + j) ----
    short4v b1p[4], b2p[4], rb1p[2], rw2p[2];
    #pragma unroll
    for (int nt = 0; nt < 4; ++nt) {
        float4 v1 = *(const float4*)&b1[e * HSz + nt * 16 + lg * 4];
        float4 v2 = *(const float4*)&b2[e * Ssz + nt * 16 + lg * 4];
        b1p[nt] = (short4v){ f2bf(v1.x), f2bf(v1.y), f2bf(v1.z), f2bf(v1.w) };
        b2p[nt] = (short4v){ f2bf(v2.x), f2bf(v2.y), f2bf(v2.z), f2bf(v2.w) };
    }
    #pragma unroll
    for (int nt = 0; nt < 2; ++nt) {
        float4 v1 = *(const float4*)&rb1[e * HRz + nt * 16 + lg * 4];
        float4 v2 = *(const float4*)&rW2[e * HRz + nt * 16 + lg * 4];
        rb1p[nt] = (short4v){ f2bf(v1.x), f2bf(v1.y), f2bf(v1.z), f2bf(v1.w) };
        rw2p[nt] = (short4v){ f2bf(v2.x), f2bf(v2.y), f2bf(v2.z), f2bf(v2.w) };
    }
    const float rb2s = rb2[e];

    __syncthreads();   // WL ready (the only barrier)

    #pragma unroll 1
    for (int t = 0; t < NTILE; ++t) {
        const int rbase = c0 + t * 128 + w * 32;     // wave's 32 rows this tile

        // ---- X: f32 loads -> bf16 fragments (both 16-row halves) ----
        bf16x8 a[2][3];
        #pragma unroll
        for (int mh = 0; mh < 2; ++mh) {
            const float* sp = state  + (size_t)(rbase + mh * 16 + lr) * Ssz + lg * 8;
            const float* ap = action + (size_t)(rbase + mh * 16 + lr) * Asz + lg * 8;
            float4 s0 = *(const float4*)(sp);
            float4 s1 = *(const float4*)(sp + 4);
            float4 s2 = *(const float4*)(sp + 32);
            float4 s3 = *(const float4*)(sp + 36);
            float4 a0 = *(const float4*)(ap);
            float4 a1 = *(const float4*)(ap + 4);
            a[mh][0] = pack8(s0, s1);
            a[mh][1] = pack8(s2, s3);
            a[mh][2] = pack8(a0, a1);
        }

        // ---- Layer 1 (state): each wf read feeds both halves ----
        f32x4 accS[2][4];
        #pragma unroll
        for (int nt = 0; nt < 4; ++nt) {
            f32x4 bi = (f32x4){ bf2f(b1p[nt][0]), bf2f(b1p[nt][1]),
                                bf2f(b1p[nt][2]), bf2f(b1p[nt][3]) };
            accS[0][nt] = bi;
            accS[1][nt] = bi;
            #pragma unroll
            for (int kk = 0; kk < 3; ++kk) {
                bf16x8 wf = *(const bf16x8*)&WL[(nt * 3 + kk) * 512 + lane * 8];
                accS[0][nt] = __builtin_amdgcn_mfma_f32_16x16x32_bf16(wf, a[0][kk], accS[0][nt], 0, 0, 0);
                accS[1][nt] = __builtin_amdgcn_mfma_f32_16x16x32_bf16(wf, a[1][kk], accS[1][nt], 0, 0, 0);
            }
        }
        // ---- Layer 1 (reward) ----
        f32x4 accR[2][2];
        #pragma unroll
        for (int nt = 0; nt < 2; ++nt) {
            f32x4 bi = (f32x4){ bf2f(rb1p[nt][0]), bf2f(rb1p[nt][1]),
                                bf2f(rb1p[nt][2]), bf2f(rb1p[nt][3]) };
            accR[0][nt] = bi;
            accR[1][nt] = bi;
            #pragma unroll
            for (int kk = 0; kk < 3; ++kk) {
                bf16x8 wf = *(const bf16x8*)&WL[6144 + (nt * 3 + kk) * 512 + lane * 8];
                accR[0][nt] = __builtin_amdgcn_mfma_f32_16x16x32_bf16(wf, a[0][kk], accR[0][nt], 0, 0, 0);
                accR[1][nt] = __builtin_amdgcn_mfma_f32_16x16x32_bf16(wf, a[1][kk], accR[1][nt], 0, 0, 0);
            }
        }

        // ---- H transpose through HT, one 16-row half at a time (wave-private, in-order) ----
        bf16x8 h[2][2];
        #pragma unroll
        for (int mh = 0; mh < 2; ++mh) {
            #pragma unroll
            for (int nt = 0; nt < 4; ++nt) {
                short4v p = { f2bf(fmaxf(accS[mh][nt][0], 0.f)),
                              f2bf(fmaxf(accS[mh][nt][1], 0.f)),
                              f2bf(fmaxf(accS[mh][nt][2], 0.f)),
                              f2bf(fmaxf(accS[mh][nt][3], 0.f)) };
                *(short4v*)&HT[w][lr][nt * 16 + lg * 4] = p;
            }
            h[mh][0] = *(const bf16x8*)&HT[w][lr][lg * 8];
            h[mh][1] = *(const bf16x8*)&HT[w][lr][32 + lg * 8];
        }

        // ---- Reward layer 2 in registers ----
        #pragma unroll
        for (int mh = 0; mh < 2; ++mh) {
            float rp = 0.f;
            #pragma unroll
            for (int nt = 0; nt < 2; ++nt) {
                rp += fmaxf(accR[mh][nt][0], 0.f) * bf2f(rw2p[nt][0]);
                rp += fmaxf(accR[mh][nt][1], 0.f) * bf2f(rw2p[nt][1]);
                rp += fmaxf(accR[mh][nt][2], 0.f) * bf2f(rw2p[nt][2]);
                rp += fmaxf(accR[mh][nt][3], 0.f) * bf2f(rw2p[nt][3]);
            }
            rp += __shfl_xor(rp, 16);
            rp += __shfl_xor(rp, 32);
            if (lane < 16)
                outR[(size_t)e * Bsz + rbase + mh * 16 + lr] =
                    fminf(fmaxf(rp + rb2s, -100.f), 200.f);
        }

        // ---- Layer 2 (state): each w2 frag read feeds both halves ----
        #pragma unroll
        for (int nt = 0; nt < 4; ++nt) {
            f32x4 bi = (f32x4){ bf2f(b2p[nt][0]), bf2f(b2p[nt][1]),
                                bf2f(b2p[nt][2]), bf2f(b2p[nt][3]) };
            f32x4 o0 = bi, o1 = bi;
            #pragma unroll
            for (int kk = 0; kk < 2; ++kk) {
                bf16x8 wf = *(const bf16x8*)&WL[9216 + (nt * 2 + kk) * 512 + lane * 8];
                o0 = __builtin_amdgcn_mfma_f32_16x16x32_bf16(wf, h[0][kk], o0, 0, 0, 0);
                o1 = __builtin_amdgcn_mfma_f32_16x16x32_bf16(wf, h[1][kk], o1, 0, 0, 0);
            }
            float4 v0 = { o0[0], o0[1], o0[2], o0[3] };
            float4 v1 = { o1[0], o1[1], o1[2], o1[3] };
            *(float4*)&outS[((size_t)e * Bsz + rbase + lr)      * Ssz + nt * 16 + lg * 4] = v0;
            *(float4*)&outS[((size_t)e * Bsz + rbase + 16 + lr) * Ssz + nt * 16 + lg * 4] = v1;
        }
    }
}

extern "C" void kernel_launch(void* const* d_in, const int* in_sizes, int n_in,
                              void* d_out, int out_size, void* d_ws, size_t ws_size,
                              hipStream_t stream) {
    const float* state  = (const float*)d_in[0];
    const float* action = (const float*)d_in[1];
    const float* W1  = (const float*)d_in[2];
    const float* b1  = (const float*)d_in[3];
    const float* W2  = (const float*)d_in[4];
    const float* b2  = (const float*)d_in[5];
    const float* rW1 = (const float*)d_in[6];
    const float* rb1 = (const float*)d_in[7];
    const float* rW2 = (const float*)d_in[8];
    const float* rb2 = (const float*)d_in[9];

    float* outS = (float*)d_out;                      // [E, B, S]
    float* outR = outS + (size_t)Esz * Bsz * Ssz;     // [E, B, 1]

    short* Wf = (short*)d_ws;                         // Esz*WELEMS bf16 fragments

    prep_w<<<(Esz * WELEMS) / PT, PT, 0, stream>>>(W1, rW1, W2, Wf);   // 416 blocks
    fused_main<<<Esz * (Bsz / CHUNK), NTM, 0, stream>>>(               // 1024 blocks
        state, action, Wf, b1, b2, rb1, rW2, rb2, outS, outR);
}

// Round 10
// 39.401 us; speedup vs baseline: 2.4782x; 2.4782x over previous
//
#include <hip/hip_runtime.h>
#include <hip/hip_bf16.h>
#include <cstdint>
#include <cstddef>

// Problem constants
#define Bsz 16384
#define Esz 16
#define Ssz 64
#define Asz 32
#define Isz 96   // S + A
#define HSz 64
#define HRz 32

#define NTM 256       // 4 waves
#define SCHUNK 512    // state-block rows
#define SNTILE 8      // SCHUNK / (4 waves * 16 rows)
#define NSB 512       // state blocks (Esz * Bsz/SCHUNK)
#define RCHUNK 1024   // reward-block rows
#define RNTILE 16
#define NRB 256       // reward blocks (Esz * Bsz/RCHUNK)

typedef __attribute__((ext_vector_type(8))) short bf16x8;
typedef __attribute__((ext_vector_type(4))) short short4v;
typedef __attribute__((ext_vector_type(4))) float f32x4;

static __device__ __forceinline__ short f2bf(float f) {
    __hip_bfloat16 b = __float2bfloat16(f);   // pairs into v_cvt_pk_bf16_f32
    return *reinterpret_cast<short*>(&b);
}
static __device__ __forceinline__ float bf2f(short s) {
    union { uint32_t u; float f; } v; v.u = ((uint32_t)(uint16_t)s) << 16; return v.f;
}
static __device__ __forceinline__ bf16x8 pack8(float4 lo, float4 hi) {
    bf16x8 r;
    r[0] = f2bf(lo.x); r[1] = f2bf(lo.y); r[2] = f2bf(lo.z); r[3] = f2bf(lo.w);
    r[4] = f2bf(hi.x); r[5] = f2bf(hi.y); r[6] = f2bf(hi.z); r[7] = f2bf(hi.w);
    return r;
}

// One kernel, two block roles. Blocks [0,NSB): state MLP (weights in VGPR,
// ~165 regs -> 3 waves/SIMD). Blocks [NSB,NSB+NRB): reward MLP (light).
// 768 blocks = 3 blocks/CU, single co-resident generation.
// Swapped mfma(Wfrag, Xfrag): D lane: m = lane&15, n = nt*16 + (lane>>4)*4 + j.
__global__ __launch_bounds__(NTM, 3)
void fused_all(const float* __restrict__ state, const float* __restrict__ action,
               const float* __restrict__ W1, const float* __restrict__ b1,
               const float* __restrict__ W2, const float* __restrict__ b2,
               const float* __restrict__ rW1, const float* __restrict__ rb1,
               const float* __restrict__ rW2, const float* __restrict__ rb2,
               float* __restrict__ outS, float* __restrict__ outR)
{
    // Per-wave H buffer [m=16][h=64], row stride 68 shorts: b64 writes /
    // b128 reads ~2-way max (free). 8704 B.
    __shared__ __align__(16) short HT[4][16][68];

    const int bid = blockIdx.x;
    const int w = threadIdx.x >> 6, lane = threadIdx.x & 63;
    const int lr = lane & 15, lg = lane >> 4;

    if (bid < NSB) {
        // ================= STATE PATH =================
        // XCD-grouping swizzle (kept from R8; mildly positive there)
        const int xcd = bid & 7;
        const int rem = bid >> 3;
        const int e   = rem & (Esz - 1);
        const int c0  = (xcd + 8 * (rem >> 4)) * SCHUNK;

        // Weight fragments: per-lane gather from f32, convert once.
        // Fragment (nt,kk): lane holds W[k=kk*32+lg*8+t][n=nt*16+lr], t=0..7.
        bf16x8 w1r[4][3], w2r[4][2];
        {
            const float* base = W1 + (size_t)e * Isz * HSz;
            #pragma unroll
            for (int nt = 0; nt < 4; ++nt)
                #pragma unroll
                for (int kk = 0; kk < 3; ++kk) {
                    const float* p = base + (kk * 32 + lg * 8) * HSz + nt * 16 + lr;
                    bf16x8 r;
                    #pragma unroll
                    for (int t = 0; t < 8; ++t) r[t] = f2bf(p[t * HSz]);
                    w1r[nt][kk] = r;
                }
        }
        {
            const float* base = W2 + (size_t)e * HSz * Ssz;
            #pragma unroll
            for (int nt = 0; nt < 4; ++nt)
                #pragma unroll
                for (int kk = 0; kk < 2; ++kk) {
                    const float* p = base + (kk * 32 + lg * 8) * Ssz + nt * 16 + lr;
                    bf16x8 r;
                    #pragma unroll
                    for (int t = 0; t < 8; ++t) r[t] = f2bf(p[t * Ssz]);
                    w2r[nt][kk] = r;
                }
        }
        // Biases packed bf16 (lane's D slots: n = nt*16 + lg*4 + j)
        short4v b1p[4], b2p[4];
        #pragma unroll
        for (int nt = 0; nt < 4; ++nt) {
            float4 v1 = *(const float4*)&b1[e * HSz + nt * 16 + lg * 4];
            float4 v2 = *(const float4*)&b2[e * Ssz + nt * 16 + lg * 4];
            b1p[nt] = (short4v){ f2bf(v1.x), f2bf(v1.y), f2bf(v1.z), f2bf(v1.w) };
            b2p[nt] = (short4v){ f2bf(v2.x), f2bf(v2.y), f2bf(v2.z), f2bf(v2.w) };
        }

        const int row0 = c0 + w * 16 + lr;           // lane's base batch row (m = lr)
        const float* sbase = state  + (size_t)row0 * Ssz + lg * 8;
        const float* abase = action + (size_t)row0 * Asz + lg * 8;

        float4 xs0 = *(const float4*)(sbase);
        float4 xs1 = *(const float4*)(sbase + 4);
        float4 xs2 = *(const float4*)(sbase + 32);
        float4 xs3 = *(const float4*)(sbase + 36);
        float4 xa0 = *(const float4*)(abase);
        float4 xa1 = *(const float4*)(abase + 4);
        bf16x8 a0 = pack8(xs0, xs1);
        bf16x8 a1 = pack8(xs2, xs3);
        bf16x8 a2 = pack8(xa0, xa1);

        #pragma unroll 1
        for (int t = 0; t < SNTILE; ++t) {
            const int tn = (t + 1) & (SNTILE - 1);   // wrap: last iter re-reads t=0 (L2-hit, discarded)
            const float* sp = sbase + (size_t)tn * 64 * Ssz;
            const float* ap = abase + (size_t)tn * 64 * Asz;
            float4 ns0 = *(const float4*)(sp);
            float4 ns1 = *(const float4*)(sp + 4);
            float4 ns2 = *(const float4*)(sp + 32);
            float4 ns3 = *(const float4*)(sp + 36);
            float4 na0 = *(const float4*)(ap);
            float4 na1 = *(const float4*)(ap + 4);

            // Layer 1: acc initialized with bias
            f32x4 accS[4];
            #pragma unroll
            for (int nt = 0; nt < 4; ++nt) {
                f32x4 acc = (f32x4){ bf2f(b1p[nt][0]), bf2f(b1p[nt][1]),
                                     bf2f(b1p[nt][2]), bf2f(b1p[nt][3]) };
                acc = __builtin_amdgcn_mfma_f32_16x16x32_bf16(w1r[nt][0], a0, acc, 0, 0, 0);
                acc = __builtin_amdgcn_mfma_f32_16x16x32_bf16(w1r[nt][1], a1, acc, 0, 0, 0);
                acc = __builtin_amdgcn_mfma_f32_16x16x32_bf16(w1r[nt][2], a2, acc, 0, 0, 0);
                accS[nt] = acc;
            }
            // H = relu(accS) -> HT (lane holds 4 consecutive h of row lr)
            #pragma unroll
            for (int nt = 0; nt < 4; ++nt) {
                short4v p = { f2bf(fmaxf(accS[nt][0], 0.f)),
                              f2bf(fmaxf(accS[nt][1], 0.f)),
                              f2bf(fmaxf(accS[nt][2], 0.f)),
                              f2bf(fmaxf(accS[nt][3], 0.f)) };
                *(short4v*)&HT[w][lr][nt * 16 + lg * 4] = p;
            }
            // Layer 2: H frags via b128 (wave-private, in-order DS)
            bf16x8 h0 = *(const bf16x8*)&HT[w][lr][lg * 8];
            bf16x8 h1 = *(const bf16x8*)&HT[w][lr][32 + lg * 8];
            #pragma unroll
            for (int nt = 0; nt < 4; ++nt) {
                f32x4 acc = (f32x4){ bf2f(b2p[nt][0]), bf2f(b2p[nt][1]),
                                     bf2f(b2p[nt][2]), bf2f(b2p[nt][3]) };
                acc = __builtin_amdgcn_mfma_f32_16x16x32_bf16(w2r[nt][0], h0, acc, 0, 0, 0);
                acc = __builtin_amdgcn_mfma_f32_16x16x32_bf16(w2r[nt][1], h1, acc, 0, 0, 0);
                float4 o = { acc[0], acc[1], acc[2], acc[3] };
                *(float4*)&outS[((size_t)e * Bsz + row0 + t * 64) * Ssz + nt * 16 + lg * 4] = o;
            }
            // Convert prefetched f32 -> next fragments (vmcnt wait lands here)
            a0 = pack8(ns0, ns1);
            a1 = pack8(ns2, ns3);
            a2 = pack8(na0, na1);
        }
    } else {
        // ================= REWARD PATH =================
        const int rbid = bid - NSB;
        const int e  = rbid & (Esz - 1);
        const int c0 = (rbid >> 4) * RCHUNK;

        bf16x8 rw1r[2][3];
        {
            const float* base = rW1 + (size_t)e * Isz * HRz;
            #pragma unroll
            for (int nt = 0; nt < 2; ++nt)
                #pragma unroll
                for (int kk = 0; kk < 3; ++kk) {
                    const float* p = base + (kk * 32 + lg * 8) * HRz + nt * 16 + lr;
                    bf16x8 r;
                    #pragma unroll
                    for (int t = 0; t < 8; ++t) r[t] = f2bf(p[t * HRz]);
                    rw1r[nt][kk] = r;
                }
        }
        short4v rb1p[2], rw2p[2];
        #pragma unroll
        for (int nt = 0; nt < 2; ++nt) {
            float4 v1 = *(const float4*)&rb1[e * HRz + nt * 16 + lg * 4];
            float4 v2 = *(const float4*)&rW2[e * HRz + nt * 16 + lg * 4];
            rb1p[nt] = (short4v){ f2bf(v1.x), f2bf(v1.y), f2bf(v1.z), f2bf(v1.w) };
            rw2p[nt] = (short4v){ f2bf(v2.x), f2bf(v2.y), f2bf(v2.z), f2bf(v2.w) };
        }
        const float rb2s = rb2[e];

        const int row0 = c0 + w * 16 + lr;
        const float* sbase = state  + (size_t)row0 * Ssz + lg * 8;
        const float* abase = action + (size_t)row0 * Asz + lg * 8;

        float4 xs0 = *(const float4*)(sbase);
        float4 xs1 = *(const float4*)(sbase + 4);
        float4 xs2 = *(const float4*)(sbase + 32);
        float4 xs3 = *(const float4*)(sbase + 36);
        float4 xa0 = *(const float4*)(abase);
        float4 xa1 = *(const float4*)(abase + 4);
        bf16x8 a0 = pack8(xs0, xs1);
        bf16x8 a1 = pack8(xs2, xs3);
        bf16x8 a2 = pack8(xa0, xa1);

        #pragma unroll 1
        for (int t = 0; t < RNTILE; ++t) {
            const int tn = (t + 1) & (RNTILE - 1);
            const float* sp = sbase + (size_t)tn * 64 * Ssz;
            const float* ap = abase + (size_t)tn * 64 * Asz;
            float4 ns0 = *(const float4*)(sp);
            float4 ns1 = *(const float4*)(sp + 4);
            float4 ns2 = *(const float4*)(sp + 32);
            float4 ns3 = *(const float4*)(sp + 36);
            float4 na0 = *(const float4*)(ap);
            float4 na1 = *(const float4*)(ap + 4);

            f32x4 accR[2];
            #pragma unroll
            for (int nt = 0; nt < 2; ++nt) {
                f32x4 acc = (f32x4){ bf2f(rb1p[nt][0]), bf2f(rb1p[nt][1]),
                                     bf2f(rb1p[nt][2]), bf2f(rb1p[nt][3]) };
                acc = __builtin_amdgcn_mfma_f32_16x16x32_bf16(rw1r[nt][0], a0, acc, 0, 0, 0);
                acc = __builtin_amdgcn_mfma_f32_16x16x32_bf16(rw1r[nt][1], a1, acc, 0, 0, 0);
                acc = __builtin_amdgcn_mfma_f32_16x16x32_bf16(rw1r[nt][2], a2, acc, 0, 0, 0);
                accR[nt] = acc;
            }
            float rp = 0.f;
            #pragma unroll
            for (int nt = 0; nt < 2; ++nt) {
                rp += fmaxf(accR[nt][0], 0.f) * bf2f(rw2p[nt][0]);
                rp += fmaxf(accR[nt][1], 0.f) * bf2f(rw2p[nt][1]);
                rp += fmaxf(accR[nt][2], 0.f) * bf2f(rw2p[nt][2]);
                rp += fmaxf(accR[nt][3], 0.f) * bf2f(rw2p[nt][3]);
            }
            rp += __shfl_xor(rp, 16);
            rp += __shfl_xor(rp, 32);
            if (lane < 16)
                outR[(size_t)e * Bsz + row0 + t * 64] =
                    fminf(fmaxf(rp + rb2s, -100.f), 200.f);

            a0 = pack8(ns0, ns1);
            a1 = pack8(ns2, ns3);
            a2 = pack8(na0, na1);
        }
    }
}

extern "C" void kernel_launch(void* const* d_in, const int* in_sizes, int n_in,
                              void* d_out, int out_size, void* d_ws, size_t ws_size,
                              hipStream_t stream) {
    const float* state  = (const float*)d_in[0];
    const float* action = (const float*)d_in[1];
    const float* W1  = (const float*)d_in[2];
    const float* b1  = (const float*)d_in[3];
    const float* W2  = (const float*)d_in[4];
    const float* b2  = (const float*)d_in[5];
    const float* rW1 = (const float*)d_in[6];
    const float* rb1 = (const float*)d_in[7];
    const float* rW2 = (const float*)d_in[8];
    const float* rb2 = (const float*)d_in[9];

    float* outS = (float*)d_out;                      // [E, B, S]
    float* outR = outS + (size_t)Esz * Bsz * Ssz;     // [E, B, 1]

    fused_all<<<NSB + NRB, NTM, 0, stream>>>(         // 768 blocks = 3/CU, 1 generation
        state, action, W1, b1, W2, b2, rW1, rb1, rW2, rb2, outS, outR);
}

// Round 12
// 27.275 us; speedup vs baseline: 3.5800x; 1.4446x over previous
//
#include <hip/hip_runtime.h>
#include <hip/hip_bf16.h>
#include <cstdint>
#include <cstddef>

// Problem constants
#define Bsz 16384
#define Esz 16
#define Ssz 64
#define Asz 32
#define Isz 96   // S + A
#define HSz 64
#define HRz 32

#define NTM 256       // 4 waves
#define CHUNK 512     // batch rows per block
#define NTILE 8       // CHUNK / (4 waves * 16 rows)

typedef __attribute__((ext_vector_type(8))) short bf16x8;
typedef __attribute__((ext_vector_type(4))) short short4v;
typedef __attribute__((ext_vector_type(4))) float f32x4;

static __device__ __forceinline__ short f2bf(float f) {
    __hip_bfloat16 b = __float2bfloat16(f);   // pairs into v_cvt_pk_bf16_f32
    return *reinterpret_cast<short*>(&b);
}
static __device__ __forceinline__ float bf2f(short s) {
    union { uint32_t u; float f; } v; v.u = ((uint32_t)(uint16_t)s) << 16; return v.f;
}
static __device__ __forceinline__ bf16x8 pack8(float4 lo, float4 hi) {
    bf16x8 r;
    r[0] = f2bf(lo.x); r[1] = f2bf(lo.y); r[2] = f2bf(lo.z); r[3] = f2bf(lo.w);
    r[4] = f2bf(hi.x); r[5] = f2bf(hi.y); r[6] = f2bf(hi.z); r[7] = f2bf(hi.w);
    return r;
}

// R8 structure (best, 29.1 us) + NONTEMPORAL output stores (ext-vector form).
// One ensemble per block; weights gathered from f32 into VGPRs; swapped-operand
// MFMAs (D lane: m = lane&15, n = nt*16+(lane>>4)*4+j). XCD swizzle keeps the
// 16 e-siblings of each batch chunk on one XCD (X L2-resident). nt-stores keep
// the 68 MB output stream from evicting X/weights out of L2.
__global__ __launch_bounds__(NTM, 2)
void fused_all(const float* __restrict__ state, const float* __restrict__ action,
               const float* __restrict__ W1, const float* __restrict__ b1,
               const float* __restrict__ W2, const float* __restrict__ b2,
               const float* __restrict__ rW1, const float* __restrict__ rb1,
               const float* __restrict__ rW2, const float* __restrict__ rb2,
               float* __restrict__ outS, float* __restrict__ outR)
{
    // Per-wave H buffer [m=16][h=64], row stride 68 shorts (136 B):
    // b64 writes / b128 reads both ~2-way max (free). 8704 B total.
    __shared__ __align__(16) short HT[4][16][68];

    // ---- XCD-aware sibling swizzle (bijective over 512 blocks) ----
    const int bid = blockIdx.x;
    const int xcd = bid & 7;
    const int rem = bid >> 3;
    const int e   = rem & (Esz - 1);
    const int c0  = (xcd + 8 * (rem >> 4)) * CHUNK;

    const int w = threadIdx.x >> 6, lane = threadIdx.x & 63;
    const int lr = lane & 15, lg = lane >> 4;

    // ---- Weight fragments: per-lane gather from f32, convert once ----
    // Fragment (nt,kk): lane holds W[k = kk*32 + lg*8 + t][n = nt*16 + lr], t=0..7.
    bf16x8 w1r[4][3], rw1r[2][3], w2r[4][2];
    {
        const float* base = W1 + (size_t)e * Isz * HSz;
        #pragma unroll
        for (int nt = 0; nt < 4; ++nt)
            #pragma unroll
            for (int kk = 0; kk < 3; ++kk) {
                const float* p = base + (kk * 32 + lg * 8) * HSz + nt * 16 + lr;
                bf16x8 r;
                #pragma unroll
                for (int t = 0; t < 8; ++t) r[t] = f2bf(p[t * HSz]);
                w1r[nt][kk] = r;
            }
    }
    {
        const float* base = rW1 + (size_t)e * Isz * HRz;
        #pragma unroll
        for (int nt = 0; nt < 2; ++nt)
            #pragma unroll
            for (int kk = 0; kk < 3; ++kk) {
                const float* p = base + (kk * 32 + lg * 8) * HRz + nt * 16 + lr;
                bf16x8 r;
                #pragma unroll
                for (int t = 0; t < 8; ++t) r[t] = f2bf(p[t * HRz]);
                rw1r[nt][kk] = r;
            }
    }
    {
        const float* base = W2 + (size_t)e * HSz * Ssz;
        #pragma unroll
        for (int nt = 0; nt < 4; ++nt)
            #pragma unroll
            for (int kk = 0; kk < 2; ++kk) {
                const float* p = base + (kk * 32 + lg * 8) * Ssz + nt * 16 + lr;
                bf16x8 r;
                #pragma unroll
                for (int t = 0; t < 8; ++t) r[t] = f2bf(p[t * Ssz]);
                w2r[nt][kk] = r;
            }
    }

    // ---- Biases packed bf16 (lane's D slots: n = nt*16 + lg*4 + j) ----
    short4v b1p[4], b2p[4], rb1p[2], rw2p[2];
    #pragma unroll
    for (int nt = 0; nt < 4; ++nt) {
        float4 v1 = *(const float4*)&b1[e * HSz + nt * 16 + lg * 4];
        float4 v2 = *(const float4*)&b2[e * Ssz + nt * 16 + lg * 4];
        b1p[nt] = (short4v){ f2bf(v1.x), f2bf(v1.y), f2bf(v1.z), f2bf(v1.w) };
        b2p[nt] = (short4v){ f2bf(v2.x), f2bf(v2.y), f2bf(v2.z), f2bf(v2.w) };
    }
    #pragma unroll
    for (int nt = 0; nt < 2; ++nt) {
        float4 v1 = *(const float4*)&rb1[e * HRz + nt * 16 + lg * 4];
        float4 v2 = *(const float4*)&rW2[e * HRz + nt * 16 + lg * 4];
        rb1p[nt] = (short4v){ f2bf(v1.x), f2bf(v1.y), f2bf(v1.z), f2bf(v1.w) };
        rw2p[nt] = (short4v){ f2bf(v2.x), f2bf(v2.y), f2bf(v2.z), f2bf(v2.w) };
    }
    const float rb2s = rb2[e];

    // ---- X pipeline: f32 loads (prefetched) -> cvt_pk -> bf16 fragments ----
    const int row0 = c0 + w * 16 + lr;               // this lane's base batch row (m = lr)
    const float* sbase = state  + (size_t)row0 * Ssz + lg * 8;
    const float* abase = action + (size_t)row0 * Asz + lg * 8;

    float4 xs0 = *(const float4*)(sbase);
    float4 xs1 = *(const float4*)(sbase + 4);
    float4 xs2 = *(const float4*)(sbase + 32);
    float4 xs3 = *(const float4*)(sbase + 36);
    float4 xa0 = *(const float4*)(abase);
    float4 xa1 = *(const float4*)(abase + 4);
    bf16x8 a0 = pack8(xs0, xs1);
    bf16x8 a1 = pack8(xs2, xs3);
    bf16x8 a2 = pack8(xa0, xa1);

    #pragma unroll 1
    for (int t = 0; t < NTILE; ++t) {
        // Prefetch next tile's f32 rows (wraps on last iter; L2-hit, discarded)
        const int tn = (t + 1) & (NTILE - 1);
        const float* sp = sbase + (size_t)tn * 64 * Ssz;
        const float* ap = abase + (size_t)tn * 64 * Asz;
        float4 ns0 = *(const float4*)(sp);
        float4 ns1 = *(const float4*)(sp + 4);
        float4 ns2 = *(const float4*)(sp + 32);
        float4 ns3 = *(const float4*)(sp + 36);
        float4 na0 = *(const float4*)(ap);
        float4 na1 = *(const float4*)(ap + 4);

        // ---- Layer 1 (state): acc initialized with bias (free add) ----
        f32x4 accS[4];
        #pragma unroll
        for (int nt = 0; nt < 4; ++nt) {
            f32x4 acc = (f32x4){ bf2f(b1p[nt][0]), bf2f(b1p[nt][1]),
                                 bf2f(b1p[nt][2]), bf2f(b1p[nt][3]) };
            acc = __builtin_amdgcn_mfma_f32_16x16x32_bf16(w1r[nt][0], a0, acc, 0, 0, 0);
            acc = __builtin_amdgcn_mfma_f32_16x16x32_bf16(w1r[nt][1], a1, acc, 0, 0, 0);
            acc = __builtin_amdgcn_mfma_f32_16x16x32_bf16(w1r[nt][2], a2, acc, 0, 0, 0);
            accS[nt] = acc;
        }
        // ---- Layer 1 (reward) ----
        f32x4 accR[2];
        #pragma unroll
        for (int nt = 0; nt < 2; ++nt) {
            f32x4 acc = (f32x4){ bf2f(rb1p[nt][0]), bf2f(rb1p[nt][1]),
                                 bf2f(rb1p[nt][2]), bf2f(rb1p[nt][3]) };
            acc = __builtin_amdgcn_mfma_f32_16x16x32_bf16(rw1r[nt][0], a0, acc, 0, 0, 0);
            acc = __builtin_amdgcn_mfma_f32_16x16x32_bf16(rw1r[nt][1], a1, acc, 0, 0, 0);
            acc = __builtin_amdgcn_mfma_f32_16x16x32_bf16(rw1r[nt][2], a2, acc, 0, 0, 0);
            accR[nt] = acc;
        }

        // ---- H = relu(accS) -> HT (lane holds 4 consecutive h of row lr) ----
        #pragma unroll
        for (int nt = 0; nt < 4; ++nt) {
            short4v p = { f2bf(fmaxf(accS[nt][0], 0.f)),
                          f2bf(fmaxf(accS[nt][1], 0.f)),
                          f2bf(fmaxf(accS[nt][2], 0.f)),
                          f2bf(fmaxf(accS[nt][3], 0.f)) };
            *(short4v*)&HT[w][lr][nt * 16 + lg * 4] = p;
        }

        // ---- Reward layer 2 in registers ----
        float rp = 0.f;
        #pragma unroll
        for (int nt = 0; nt < 2; ++nt) {
            rp += fmaxf(accR[nt][0], 0.f) * bf2f(rw2p[nt][0]);
            rp += fmaxf(accR[nt][1], 0.f) * bf2f(rw2p[nt][1]);
            rp += fmaxf(accR[nt][2], 0.f) * bf2f(rw2p[nt][2]);
            rp += fmaxf(accR[nt][3], 0.f) * bf2f(rw2p[nt][3]);
        }
        rp += __shfl_xor(rp, 16);
        rp += __shfl_xor(rp, 32);
        if (lane < 16)
            __builtin_nontemporal_store(fminf(fmaxf(rp + rb2s, -100.f), 200.f),
                                        &outR[(size_t)e * Bsz + row0 + t * 64]);

        // ---- Layer 2 (state): H frags via b128 (wave-private, in-order DS) ----
        bf16x8 h0 = *(const bf16x8*)&HT[w][lr][lg * 8];
        bf16x8 h1 = *(const bf16x8*)&HT[w][lr][32 + lg * 8];
        #pragma unroll
        for (int nt = 0; nt < 4; ++nt) {
            f32x4 acc = (f32x4){ bf2f(b2p[nt][0]), bf2f(b2p[nt][1]),
                                 bf2f(b2p[nt][2]), bf2f(b2p[nt][3]) };
            acc = __builtin_amdgcn_mfma_f32_16x16x32_bf16(w2r[nt][0], h0, acc, 0, 0, 0);
            acc = __builtin_amdgcn_mfma_f32_16x16x32_bf16(w2r[nt][1], h1, acc, 0, 0, 0);
            // nt-store of the ext-vector accumulator (builtin accepts vector-of-float)
            __builtin_nontemporal_store(acc,
                (f32x4*)&outS[((size_t)e * Bsz + row0 + t * 64) * Ssz + nt * 16 + lg * 4]);
        }

        // ---- Convert prefetched f32 -> current fragments (vmcnt wait lands here) ----
        a0 = pack8(ns0, ns1);
        a1 = pack8(ns2, ns3);
        a2 = pack8(na0, na1);
    }
}

extern "C" void kernel_launch(void* const* d_in, const int* in_sizes, int n_in,
                              void* d_out, int out_size, void* d_ws, size_t ws_size,
                              hipStream_t stream) {
    const float* state  = (const float*)d_in[0];
    const float* action = (const float*)d_in[1];
    const float* W1  = (const float*)d_in[2];
    const float* b1  = (const float*)d_in[3];
    const float* W2  = (const float*)d_in[4];
    const float* b2  = (const float*)d_in[5];
    const float* rW1 = (const float*)d_in[6];
    const float* rb1 = (const float*)d_in[7];
    const float* rW2 = (const float*)d_in[8];
    const float* rb2 = (const float*)d_in[9];

    float* outS = (float*)d_out;                      // [E, B, S]
    float* outR = outS + (size_t)Esz * Bsz * Ssz;     // [E, B, 1]

    fused_all<<<Esz * (Bsz / CHUNK), NTM, 0, stream>>>(   // 512 blocks, 1 generation
        state, action, W1, b1, W2, b2, rW1, rb1, rW2, rb2, outS, outR);
}